// Round 1
// 431.065 us; speedup vs baseline: 1.1999x; 1.1999x over previous
//
#include <hip/hip_runtime.h>

#define IN_DIM 300
#define MEM    150
#define GP     160   // padded per-gate pitch
#define GW     640   // 4 gates * GP
#define KX     300   // x-proj real K
#define KXP    320   // x-proj padded K (bf16 A buffer pitch)
#define KH     160   // level GEMM K (padded, H buffer is pre-padded)
#define NLEAF  65536
#define NTOT   87381
#define DEPTH  9

static const int SIZES[DEPTH] = {65536,16384,4096,1024,256,64,16,4,1};
static const int OFF[DEPTH]   = {0,65536,81920,86016,87040,87296,87360,87376,87380};

typedef __attribute__((ext_vector_type(8))) short short8;
typedef __attribute__((ext_vector_type(4))) float f32x4;

__device__ __forceinline__ float sigf(float x) { return 1.0f / (1.0f + __expf(-x)); }
__device__ __forceinline__ float tanhf_fast(float x) {
    float e = __expf(2.0f * x);
    return 1.0f - 2.0f / (e + 1.0f);
}
__device__ __forceinline__ unsigned short f2bf(float f) {
    union { float f; unsigned u; } v; v.f = f;
    unsigned r = v.u + 0x7FFF + ((v.u >> 16) & 1);
    return (unsigned short)(r >> 16);
}
__device__ __forceinline__ float bf2f(unsigned short u) {
    union { unsigned u; float f; } v; v.u = ((unsigned)u) << 16; return v.f;
}

// async global->LDS, 16 bytes per lane
typedef const __attribute__((address_space(1))) unsigned int* as1_u32p;
typedef __attribute__((address_space(3))) unsigned int* as3_u32p;
__device__ __forceinline__ void gl_lds16(const unsigned short* g, unsigned short* l) {
    __builtin_amdgcn_global_load_lds((as1_u32p)g, (as3_u32p)l, 16, 0, 0);
}

// ---------------- weight packing: transposed bf16 weights + fp32 biases --------
__global__ void pack_weights(const float* __restrict__ Wix, const float* __restrict__ Wfx,
                             const float* __restrict__ Wux, const float* __restrict__ Wox,
                             const float* __restrict__ bix, const float* __restrict__ bfx,
                             const float* __restrict__ bux, const float* __restrict__ box,
                             const float* __restrict__ Wih, const float* __restrict__ Wfh,
                             const float* __restrict__ Wuh, const float* __restrict__ Woh,
                             const float* __restrict__ bfh,
                             unsigned short* __restrict__ W4xT, unsigned short* __restrict__ W4hT,
                             float* __restrict__ b4x, float* __restrict__ b4hf)
{
    int stride = gridDim.x * blockDim.x;
    int tid = blockIdx.x * blockDim.x + threadIdx.x;
    for (int idx = tid; idx < GW * KXP; idx += stride) {
        int c = idx / KXP, k = idx - c * KXP;
        int g = c / GP, j = c - g * GP;
        const float* W = (g == 0) ? Wix : (g == 1) ? Wfx : (g == 2) ? Wux : Wox;
        W4xT[idx] = (j < MEM && k < KX) ? f2bf(W[k * MEM + j]) : (unsigned short)0;
    }
    for (int idx = tid; idx < GW * KH; idx += stride) {
        int c = idx / KH, k = idx - c * KH;
        int g = c / GP, j = c - g * GP;
        const float* W = (g == 0) ? Wih : (g == 1) ? Wfh : (g == 2) ? Wuh : Woh;
        W4hT[idx] = (j < MEM && k < MEM) ? f2bf(W[k * MEM + j]) : (unsigned short)0;
    }
    for (int idx = tid; idx < GW; idx += stride) {
        int g = idx / GP, j = idx - g * GP;
        const float* b = (g == 0) ? bix : (g == 1) ? bfx : (g == 2) ? bux : box;
        b4x[idx]  = (j < MEM) ? b[j] : 0.0f;
        b4hf[idx] = (g == 1 && j < MEM) ? bfh[j] : 0.0f;
    }
}

// ---------------- embs fp32 -> bf16, padded to KXP cols ------------------------
__global__ void conv_embs(const float* __restrict__ embs, unsigned short* __restrict__ Abf)
{
    int idx = blockIdx.x * 256 + threadIdx.x;
    if (idx >= NTOT * (KXP / 8)) return;
    int n = idx / (KXP / 8), c = idx - n * (KXP / 8);
    int c0 = c * 8;
    unsigned short v[8];
    if (c0 + 8 <= KX) {
        const float4* p = (const float4*)(embs + (size_t)n * KX + c0);
        float4 f0 = p[0], f1 = p[1];
        v[0]=f2bf(f0.x); v[1]=f2bf(f0.y); v[2]=f2bf(f0.z); v[3]=f2bf(f0.w);
        v[4]=f2bf(f1.x); v[5]=f2bf(f1.y); v[6]=f2bf(f1.z); v[7]=f2bf(f1.w);
    } else {
        const float* row = embs + (size_t)n * KX;
        #pragma unroll
        for (int j = 0; j < 8; ++j) {
            int col = c0 + j;
            v[j] = (col < KX) ? f2bf(row[col]) : (unsigned short)0;
        }
    }
    *(short8*)&Abf[(size_t)n * KXP + c0] = *(short8*)v;
}

// ---------------- bf16 MFMA GEMM with global_load_lds staging ------------------
// C[M x 640] = A[M x KPAD] @ BT^T + bias, Cout bf16 pitch GW.
// Tile 128x128, BK=32, double-buffered LDS, ONE barrier per K-step
// (prefetch tile k+1 overlaps ds_read+MFMA of tile k).
// LDS layout linear [128][32] (required by global_load_lds); k-chunk XOR
// swizzle applied on BOTH global source addr and ds_read addr (rule #21).
// Grid: 1D, nwg = 5 * mtiles; desired order m-tile major / n-tile fast so the
// 5 n-tiles sharing one A-panel are dispatch-adjacent; bijective XCD swizzle.
template<int KPAD>
__global__ __launch_bounds__(256) void gemm_lds(
    const unsigned short* __restrict__ A, int M,
    const unsigned short* __restrict__ BT,
    const float* __restrict__ bias,
    unsigned short* __restrict__ Cout)
{
    __shared__ __align__(16) unsigned short As[2][128 * 32];
    __shared__ __align__(16) unsigned short Bs[2][128 * 32];

    // bijective XCD swizzle (m204)
    const int nwg = gridDim.x;
    const int orig = blockIdx.x;
    const int qq = nwg >> 3, rr = nwg & 7;
    const int xcd = orig & 7, lin = orig >> 3;
    const int dd = (xcd < rr ? xcd * (qq + 1) : rr * (qq + 1) + (xcd - rr) * qq) + lin;
    const int mtile = dd / 5, ntile = dd - mtile * 5;

    const int t = threadIdx.x;
    const int m0 = mtile * 128, n0 = ntile * 128;
    const int l = t & 63, w = t >> 6;
    const int l15 = l & 15, q = l >> 4;
    const int wm = (w & 1) * 64, wn = (w >> 1) * 64;

    // staging: thread t covers LDS 16B chunk at elem t*8 (issue0: rows 0..63)
    // and 2048 + t*8 (issue1: rows 64..127). row = t>>2, k-chunk = t&3,
    // source k-chunk XOR-swizzled by (row&3) (same for row+64).
    const int srow = t >> 2;
    const int scol = ((t & 3) ^ (srow & 3)) * 8;   // elems
    int gr0 = m0 + srow;      if (gr0 >= M) gr0 = M - 1;
    int gr1 = m0 + 64 + srow; if (gr1 >= M) gr1 = M - 1;
    const unsigned short* a0 = A + (size_t)gr0 * KPAD + scol;
    const unsigned short* a1 = A + (size_t)gr1 * KPAD + scol;
    const unsigned short* b0 = BT + (size_t)(n0 + srow) * KPAD + scol;
    const unsigned short* b1 = BT + (size_t)(n0 + 64 + srow) * KPAD + scol;

    f32x4 acc[4][4];
    #pragma unroll
    for (int i = 0; i < 4; ++i)
        #pragma unroll
        for (int j = 0; j < 4; ++j)
            acc[i][j] = (f32x4){0.f, 0.f, 0.f, 0.f};

    const int kiters = KPAD >> 5;
    // prologue: stage tile 0 into buf 0
    gl_lds16(a0, &As[0][t * 8]);
    gl_lds16(a1, &As[0][2048 + t * 8]);
    gl_lds16(b0, &Bs[0][t * 8]);
    gl_lds16(b1, &Bs[0][2048 + t * 8]);
    __syncthreads();

    int cur = 0;
    for (int kt = 0; kt < kiters; ++kt) {
        if (kt + 1 < kiters) {
            const int ko = (kt + 1) << 5;
            const int nb = cur ^ 1;
            gl_lds16(a0 + ko, &As[nb][t * 8]);
            gl_lds16(a1 + ko, &As[nb][2048 + t * 8]);
            gl_lds16(b0 + ko, &Bs[nb][t * 8]);
            gl_lds16(b1 + ko, &Bs[nb][2048 + t * 8]);
        }
        short8 a[4], b[4];
        const int csw = (q ^ (l15 & 3)) * 8;   // de-swizzled k-chunk
        #pragma unroll
        for (int i = 0; i < 4; ++i)
            a[i] = *(const short8*)&As[cur][(wm + i * 16 + l15) * 32 + csw];
        #pragma unroll
        for (int j = 0; j < 4; ++j)
            b[j] = *(const short8*)&Bs[cur][(wn + j * 16 + l15) * 32 + csw];
        #pragma unroll
        for (int i = 0; i < 4; ++i)
            #pragma unroll
            for (int j = 0; j < 4; ++j)
                acc[i][j] = __builtin_amdgcn_mfma_f32_16x16x32_bf16(a[i], b[j], acc[i][j], 0, 0, 0);
        __syncthreads();   // drains vmcnt (prefetch landed) + lgkm (reads done)
        cur ^= 1;
    }

    // epilogue: bias + bf16 store. C/D: row = q*4+reg, col = lane&15
    float bj[4];
    #pragma unroll
    for (int j = 0; j < 4; ++j) bj[j] = bias[n0 + wn + j * 16 + l15];
    #pragma unroll
    for (int i = 0; i < 4; ++i) {
        #pragma unroll
        for (int r = 0; r < 4; ++r) {
            int grow = m0 + wm + i * 16 + q * 4 + r;
            if (grow < M) {
                unsigned short* crow = Cout + (size_t)grow * GW;
                #pragma unroll
                for (int j = 0; j < 4; ++j)
                    crow[n0 + wn + j * 16 + l15] = f2bf(acc[i][j][r] + bj[j]);
            }
        }
    }
}

// ---------------- leaf elementwise: gates i,u,o -> c,h,Hbf ---------------------
__global__ void leaf_ew(const unsigned short* __restrict__ PG,
                        const float* __restrict__ bih, const float* __restrict__ buh,
                        const float* __restrict__ boh,
                        float* __restrict__ out, float* __restrict__ C,
                        unsigned short* __restrict__ Hbf)
{
    int idx = blockIdx.x * 256 + threadIdx.x;
    if (idx >= NLEAF * MEM) return;
    int n = idx / MEM, m = idx - n * MEM;
    const unsigned short* row = PG + (size_t)n * GW;
    float ip = bf2f(row[m])          + bih[m];
    float up = bf2f(row[2 * GP + m]) + buh[m];
    float op = bf2f(row[3 * GP + m]) + boh[m];
    float i = sigf(ip), u = tanhf_fast(up), o = sigf(op);
    float c = i * u;
    float h = o * tanhf_fast(c);
    out[idx] = h;
    C[idx] = c;
    Hbf[(size_t)n * KH + m] = f2bf(h);
    if (m < KH - MEM) Hbf[(size_t)n * KH + MEM + m] = 0;   // zero pad cols
}

// ---------------- internal-level elementwise ------------------------------------
__global__ void level_ew(const unsigned short* __restrict__ G,
                         const unsigned short* __restrict__ P,
                         const float* __restrict__ Cprev,
                         const float* __restrict__ bih, const float* __restrict__ buh,
                         const float* __restrict__ boh,
                         float* __restrict__ outRow, float* __restrict__ Crow,
                         unsigned short* __restrict__ HbfRow, int n)
{
    int idx = blockIdx.x * 256 + threadIdx.x;
    if (idx >= n * MEM) return;
    int nn = idx / MEM, m = idx - nn * MEM;
    const unsigned short* xr = P + (size_t)nn * GW;
    float ip = bf2f(xr[m]) + bih[m];
    float fx = bf2f(xr[GP + m]);           // x@W_fx + b_fx
    float up = bf2f(xr[2 * GP + m]) + buh[m];
    float op = bf2f(xr[3 * GP + m]) + boh[m];
    float fc = 0.0f;
    #pragma unroll
    for (int k = 0; k < 4; ++k) {
        const unsigned short* gr = G + (size_t)(4 * nn + k) * GW;
        ip += bf2f(gr[m]);
        up += bf2f(gr[2 * GP + m]);
        op += bf2f(gr[3 * GP + m]);
        float f = sigf(fx + bf2f(gr[GP + m]));  // + (h_k@W_fh + b_fh)
        fc += f * Cprev[(4 * nn + k) * MEM + m];
    }
    float i = sigf(ip), u = tanhf_fast(up), o = sigf(op);
    float c = i * u + fc;
    float h = o * tanhf_fast(c);
    outRow[idx] = h;
    Crow[idx] = c;
    HbfRow[(size_t)nn * KH + m] = f2bf(h);
    if (m < KH - MEM) HbfRow[(size_t)nn * KH + MEM + m] = 0;
}

extern "C" void kernel_launch(void* const* d_in, const int* in_sizes, int n_in,
                              void* d_out, int out_size, void* d_ws, size_t ws_size,
                              hipStream_t stream)
{
    (void)in_sizes; (void)n_in; (void)out_size;
    const float* embs = (const float*)d_in[0];
    const float* Wix = (const float*)d_in[1];  const float* bix = (const float*)d_in[2];
    const float* Wfx = (const float*)d_in[3];  const float* bfx = (const float*)d_in[4];
    const float* Wux = (const float*)d_in[5];  const float* bux = (const float*)d_in[6];
    const float* Wox = (const float*)d_in[7];  const float* box = (const float*)d_in[8];
    const float* Wih = (const float*)d_in[9];  const float* bih = (const float*)d_in[10];
    const float* Wfh = (const float*)d_in[11]; const float* bfh = (const float*)d_in[12];
    const float* Wuh = (const float*)d_in[13]; const float* buh = (const float*)d_in[14];
    const float* Woh = (const float*)d_in[15]; const float* boh = (const float*)d_in[16];
    float* out = (float*)d_out;

    char* p = (char*)d_ws;
    auto alloc = [&](size_t bytes) -> char* {
        char* r = p;
        p += (bytes + 255) & ~(size_t)255;
        return r;
    };
    unsigned short* PG   = (unsigned short*)alloc((size_t)NTOT * GW * 2);
    float*          C    = (float*)alloc((size_t)NTOT * MEM * 4);
    unsigned short* Hbf  = (unsigned short*)alloc((size_t)NTOT * KH * 2);
    unsigned short* W4xT = (unsigned short*)alloc((size_t)GW * KXP * 2);
    unsigned short* W4hT = (unsigned short*)alloc((size_t)GW * KH * 2);
    float*          b4x  = (float*)alloc(GW * 4);
    float*          b4hf = (float*)alloc(GW * 4);
    if ((size_t)(p - (char*)d_ws) > ws_size) return;  // ws too small: bail

    // Abf (bf16 embs, NTOT x KXP = 55.9 MB) ALIASES the C+Hbf region (80.4 MB):
    // its last read (x-proj GEMM) strictly precedes the first write of C/Hbf
    // (leaf_ew) in stream order.
    unsigned short* Abf = (unsigned short*)C;

    pack_weights<<<128, 256, 0, stream>>>(Wix, Wfx, Wux, Wox, bix, bfx, bux, box,
                                          Wih, Wfh, Wuh, Woh, bfh,
                                          W4xT, W4hT, b4x, b4hf);

    // fp32 -> bf16 conversion of all node embeddings (padded K)
    conv_embs<<<(NTOT * (KXP / 8) + 255) / 256, 256, 0, stream>>>(embs, Abf);

    // x-projections for ALL nodes (row = global node id), bf16 out
    {
        int mt = (NTOT + 127) / 128;
        gemm_lds<KXP><<<mt * 5, 256, 0, stream>>>(Abf, NTOT, W4xT, b4x, PG);
    }

    // leaves
    leaf_ew<<<(NLEAF * MEM + 255) / 256, 256, 0, stream>>>(PG, bih, buh, boh, out, C, Hbf);

    // internal levels (sequential)
    for (int d = 1; d < DEPTH; ++d) {
        int nprev = SIZES[d - 1];
        int n = SIZES[d];
        int mt = (nprev + 127) / 128;
        // G = H_prev @ W4h (+ b_fh on f gate), overwrites PG rows [0, nprev) —
        // always strictly below this level's x-proj rows (OFF[d] >= 65536).
        gemm_lds<KH><<<mt * 5, 256, 0, stream>>>(
            Hbf + (size_t)OFF[d - 1] * KH, nprev, W4hT, b4hf, PG);
        level_ew<<<(n * MEM + 255) / 256, 256, 0, stream>>>(
            PG, PG + (size_t)OFF[d] * GW,
            C + (size_t)OFF[d - 1] * MEM,
            bih, buh, boh,
            out + (size_t)OFF[d] * MEM, C + (size_t)OFF[d] * MEM,
            Hbf + (size_t)OFF[d] * KH, n);
    }
}